// Round 9
// baseline (127.640 us; speedup 1.0000x reference)
//
#include <hip/hip_runtime.h>
#include <math.h>

// DotProductAttention B=64,S=1024,D=64 fp32, bf16-MFMA flash attention.
// Round 11: RESUBMIT of round-10 (container infra failure, no kernel signal;
// same precedent as round 6/7). Amortize shared overhead over 2x queries.
// Evidence: P-in-reg cut LDS traffic 20% (conflicts -27%) but dur only -4%
// -> no single pipe saturated; per-work-unit envelope (LDS reads + staging
// VALU + barriers) is the floor, paid once per 16-query wave. All 4 waves
// read IDENTICAL K/V LDS addresses; each 64-key iter pays 2 barriers + full
// stage for only 16 queries/wave.
// Change: BQ=128 -> each wave owns TWO q-tiles. ka/vb fragments read ONCE
// feed both q-tiles' MFMAs: per work-unit LDS reads 16->8, staging writes
// and barriers halve, K/V VMEM halves. Softmax/MFMA per unit unchanged.
// Grid 512 (2 blocks/CU); VGPR ~140 (launch_bounds(256,1): allocator NOT
// squeezed -- round-1 spill lesson); 2 waves/SIMD suffices.
// Kept: P-in-register slot permutation (r9), defer-rescale THR=8 (r9),
// bare-barrier + lgkm-only discipline (r8), batch skew (r5/r6).

#define BATCH 64
#define SEQ   1024
#define DIM   64
#define BQ    128          // queries per block (4 waves x 2 qtiles x 16)
#define BC    64           // keys per iteration
#define NKT   (SEQ / BC)   // 16
#define LSTR  72           // LDS row stride in bf16 (144 B)
#define QSCALE 0.18033688011112442f   // 0.125 * log2(e)
#define MASKED -1.0e6f
#define THR    8.0f        // defer-rescale threshold (exp2 domain)

typedef __attribute__((ext_vector_type(8))) short bf16x8;
typedef __attribute__((ext_vector_type(4))) float f32x4;

__device__ __forceinline__ uint pack2_trunc(float lo, float hi) {
    return __builtin_amdgcn_perm(__float_as_uint(hi), __float_as_uint(lo), 0x07060302);
}
__device__ __forceinline__ ushort f2bf_rne(float x) {
    uint u = __float_as_uint(x);
    return (ushort)((u + 0x7fffu + ((u >> 16) & 1u)) >> 16);
}

__global__ __launch_bounds__(256, 1) void attn_mfma_flash5(
    const float* __restrict__ q, const float* __restrict__ k,
    const float* __restrict__ v, const int* __restrict__ valid_lens,
    float* __restrict__ out)
{
    __shared__ ushort Ks[BC * LSTR];   // [key][d]
    __shared__ ushort Vt[DIM * LSTR];  // [d][slot]  (slot = permuted key)

    const int t    = threadIdx.x;
    const int wave = t >> 6;
    const int wl   = t & 63;
    const int QD   = wl >> 4;          // quad 0..3
    const int li   = wl & 15;          // lane-in-quad 0..15
    // decode: 512 blocks = 64 batches x 8 q-blocks of 128 queries.
    // skewed so co-resident blocks (spacing 256 -> grp+4) hit different batches.
    const int g    = blockIdx.x;
    const int grp  = g >> 6;                  // 0..7 q-block
    const int b    = ((g & 63) + grp) & 63;   // de-aliased batch
    const int q0   = grp * BQ;
    const int vl   = valid_lens[b];

    const size_t boff = (size_t)b * SEQ * DIM;

    // ---- Q fragments for BOTH q-tiles, pre-scaled, in registers ----
    bf16x8 qbA[2], qbB[2];
    {
        #pragma unroll
        for (int half = 0; half < 2; half++) {
            const float* qrow = q + boff
                + (size_t)(q0 + half * 64 + wave * 16 + li) * DIM + QD * 8;
            #pragma unroll
            for (int kc = 0; kc < 2; kc++) {
                float4 a = *(const float4*)(qrow + kc * 32);
                float4 c = *(const float4*)(qrow + kc * 32 + 4);
                union { bf16x8 v; ushort u[8]; } tmp;
                tmp.u[0] = f2bf_rne(a.x * QSCALE);
                tmp.u[1] = f2bf_rne(a.y * QSCALE);
                tmp.u[2] = f2bf_rne(a.z * QSCALE);
                tmp.u[3] = f2bf_rne(a.w * QSCALE);
                tmp.u[4] = f2bf_rne(c.x * QSCALE);
                tmp.u[5] = f2bf_rne(c.y * QSCALE);
                tmp.u[6] = f2bf_rne(c.z * QSCALE);
                tmp.u[7] = f2bf_rne(c.w * QSCALE);
                if (half == 0) qbA[kc] = tmp.v; else qbB[kc] = tmp.v;
            }
        }
    }

    const int it_max = (vl == 0) ? NKT : ((vl + BC - 1) >> 6);

    // ---- prefetch registers (block stages ONE 64x64 K and V tile) ----
    float4 kf[4];
    float  vf[2][8];

    // V slot permutation (proven r9): slot ko*8+j holds key
    //   kb + ((j>>2)<<5) + (j&3), kb = (ko>>2)*16 + (ko&3)*4
    auto load_tile = [&](int it) {
        const float4* kg = (const float4*)(k + boff + (size_t)it * BC * DIM);
        #pragma unroll
        for (int i = 0; i < 4; i++) kf[i] = kg[t + 256 * i];
        const float* vgf = v + boff + (size_t)it * BC * DIM;
        #pragma unroll
        for (int i = 0; i < 2; i++) {
            int slot = t + 256 * i;
            int d = slot & 63, ko = slot >> 6;
            int kb = (ko >> 2) * 16 + (ko & 3) * 4;
            #pragma unroll
            for (int j = 0; j < 8; j++) {
                int kk = kb + ((j >> 2) << 5) + (j & 3);
                vf[i][j] = vgf[(size_t)kk * DIM + d];
            }
        }
    };

    auto stage = [&]() {
        #pragma unroll
        for (int i = 0; i < 4; i++) {
            int idx = t + 256 * i;
            int row = idx >> 4, c4 = idx & 15;
            uint2 w;
            w.x = pack2_trunc(kf[i].x, kf[i].y);
            w.y = pack2_trunc(kf[i].z, kf[i].w);
            *(uint2*)&Ks[row * LSTR + c4 * 4] = w;
        }
        #pragma unroll
        for (int i = 0; i < 2; i++) {
            int slot = t + 256 * i;
            int d = slot & 63, ko = slot >> 6;
            uint4 w;
            w.x = pack2_trunc(vf[i][0], vf[i][1]);
            w.y = pack2_trunc(vf[i][2], vf[i][3]);
            w.z = pack2_trunc(vf[i][4], vf[i][5]);
            w.w = pack2_trunc(vf[i][6], vf[i][7]);
            *(uint4*)&Vt[d * LSTR + ko * 8] = w;
        }
    };

    float mA = -INFINITY, lA = 0.f, mB = -INFINITY, lB = 0.f;
    f32x4 accA[4], accB[4];
    #pragma unroll
    for (int dt = 0; dt < 4; dt++) {
        accA[dt] = (f32x4){0.f, 0.f, 0.f, 0.f};
        accB[dt] = (f32x4){0.f, 0.f, 0.f, 0.f};
    }

    load_tile(0);

    for (int it = 0; it < it_max; it++) {
        // barrier A: all waves done reading Ks/Vt of previous tile
        __builtin_amdgcn_sched_barrier(0);
        __builtin_amdgcn_s_barrier();
        __builtin_amdgcn_sched_barrier(0);

        stage();
        if (it + 1 < it_max) load_tile(it + 1);    // vmcnt floats across barrier B

        // barrier B: staging visible (lgkm only; vmcnt NOT drained)
        __builtin_amdgcn_sched_barrier(0);
        asm volatile("s_waitcnt lgkmcnt(0)" ::: "memory");
        __builtin_amdgcn_s_barrier();
        __builtin_amdgcn_sched_barrier(0);

        // ---- S^T = K x Q^T for BOTH q-tiles; ka read ONCE ----
        f32x4 scA[4], scB[4];
        #pragma unroll
        for (int kt = 0; kt < 4; kt++) {
            bf16x8 ka0 = *(const bf16x8*)&Ks[(kt * 16 + li) * LSTR + QD * 8];
            bf16x8 ka1 = *(const bf16x8*)&Ks[(kt * 16 + li) * LSTR + 32 + QD * 8];
            f32x4 cA = (f32x4){0.f, 0.f, 0.f, 0.f};
            cA = __builtin_amdgcn_mfma_f32_16x16x32_bf16(ka0, qbA[0], cA, 0, 0, 0);
            cA = __builtin_amdgcn_mfma_f32_16x16x32_bf16(ka1, qbA[1], cA, 0, 0, 0);
            scA[kt] = cA;
            f32x4 cB = (f32x4){0.f, 0.f, 0.f, 0.f};
            cB = __builtin_amdgcn_mfma_f32_16x16x32_bf16(ka0, qbB[0], cB, 0, 0, 0);
            cB = __builtin_amdgcn_mfma_f32_16x16x32_bf16(ka1, qbB[1], cB, 0, 0, 0);
            scB[kt] = cB;
        }

        // ---- mask (boundary/invalid tiles only) ----
        const int kbase = it * BC;
        if (kbase + BC > vl) {
            #pragma unroll
            for (int kt = 0; kt < 4; kt++)
                #pragma unroll
                for (int r = 0; r < 4; r++) {
                    int key = kbase + kt * 16 + QD * 4 + r;
                    if (key >= vl) { scA[kt][r] = MASKED; scB[kt][r] = MASKED; }
                }
        }

        // ---- online softmax x2 (exp2 domain, defer-rescale THR=8) ----
        union { bf16x8 v; uint u[4]; } pA0, pA1, pB0, pB1;
        {
            float mt = -INFINITY;
            #pragma unroll
            for (int kt = 0; kt < 4; kt++)
                #pragma unroll
                for (int r = 0; r < 4; r++) mt = fmaxf(mt, scA[kt][r]);
            mt = fmaxf(mt, __shfl_xor(mt, 16, 64));
            mt = fmaxf(mt, __shfl_xor(mt, 32, 64));
            if (!__all(mt - mA <= THR)) {
                float mn = fmaxf(mA, mt);
                float alpha = exp2f(mA - mn);
                mA = mn; lA *= alpha;
                float a0 = __shfl(alpha, QD * 4 + 0, 64);
                float a1 = __shfl(alpha, QD * 4 + 1, 64);
                float a2 = __shfl(alpha, QD * 4 + 2, 64);
                float a3 = __shfl(alpha, QD * 4 + 3, 64);
                #pragma unroll
                for (int dt = 0; dt < 4; dt++) {
                    accA[dt][0] *= a0; accA[dt][1] *= a1;
                    accA[dt][2] *= a2; accA[dt][3] *= a3;
                }
            }
            float p00 = exp2f(scA[0][0] - mA), p01 = exp2f(scA[0][1] - mA);
            float p02 = exp2f(scA[0][2] - mA), p03 = exp2f(scA[0][3] - mA);
            float p10 = exp2f(scA[1][0] - mA), p11 = exp2f(scA[1][1] - mA);
            float p12 = exp2f(scA[1][2] - mA), p13 = exp2f(scA[1][3] - mA);
            float p20 = exp2f(scA[2][0] - mA), p21 = exp2f(scA[2][1] - mA);
            float p22 = exp2f(scA[2][2] - mA), p23 = exp2f(scA[2][3] - mA);
            float p30 = exp2f(scA[3][0] - mA), p31 = exp2f(scA[3][1] - mA);
            float p32 = exp2f(scA[3][2] - mA), p33 = exp2f(scA[3][3] - mA);
            float ls = ((p00 + p01) + (p02 + p03)) + ((p10 + p11) + (p12 + p13))
                     + ((p20 + p21) + (p22 + p23)) + ((p30 + p31) + (p32 + p33));
            pA0.u[0] = pack2_trunc(p00, p01); pA0.u[1] = pack2_trunc(p02, p03);
            pA0.u[2] = pack2_trunc(p20, p21); pA0.u[3] = pack2_trunc(p22, p23);
            pA1.u[0] = pack2_trunc(p10, p11); pA1.u[1] = pack2_trunc(p12, p13);
            pA1.u[2] = pack2_trunc(p30, p31); pA1.u[3] = pack2_trunc(p32, p33);
            ls += __shfl_xor(ls, 16, 64);
            ls += __shfl_xor(ls, 32, 64);
            lA += ls;
        }
        {
            float mt = -INFINITY;
            #pragma unroll
            for (int kt = 0; kt < 4; kt++)
                #pragma unroll
                for (int r = 0; r < 4; r++) mt = fmaxf(mt, scB[kt][r]);
            mt = fmaxf(mt, __shfl_xor(mt, 16, 64));
            mt = fmaxf(mt, __shfl_xor(mt, 32, 64));
            if (!__all(mt - mB <= THR)) {
                float mn = fmaxf(mB, mt);
                float alpha = exp2f(mB - mn);
                mB = mn; lB *= alpha;
                float a0 = __shfl(alpha, QD * 4 + 0, 64);
                float a1 = __shfl(alpha, QD * 4 + 1, 64);
                float a2 = __shfl(alpha, QD * 4 + 2, 64);
                float a3 = __shfl(alpha, QD * 4 + 3, 64);
                #pragma unroll
                for (int dt = 0; dt < 4; dt++) {
                    accB[dt][0] *= a0; accB[dt][1] *= a1;
                    accB[dt][2] *= a2; accB[dt][3] *= a3;
                }
            }
            float p00 = exp2f(scB[0][0] - mB), p01 = exp2f(scB[0][1] - mB);
            float p02 = exp2f(scB[0][2] - mB), p03 = exp2f(scB[0][3] - mB);
            float p10 = exp2f(scB[1][0] - mB), p11 = exp2f(scB[1][1] - mB);
            float p12 = exp2f(scB[1][2] - mB), p13 = exp2f(scB[1][3] - mB);
            float p20 = exp2f(scB[2][0] - mB), p21 = exp2f(scB[2][1] - mB);
            float p22 = exp2f(scB[2][2] - mB), p23 = exp2f(scB[2][3] - mB);
            float p30 = exp2f(scB[3][0] - mB), p31 = exp2f(scB[3][1] - mB);
            float p32 = exp2f(scB[3][2] - mB), p33 = exp2f(scB[3][3] - mB);
            float ls = ((p00 + p01) + (p02 + p03)) + ((p10 + p11) + (p12 + p13))
                     + ((p20 + p21) + (p22 + p23)) + ((p30 + p31) + (p32 + p33));
            pB0.u[0] = pack2_trunc(p00, p01); pB0.u[1] = pack2_trunc(p02, p03);
            pB0.u[2] = pack2_trunc(p20, p21); pB0.u[3] = pack2_trunc(p22, p23);
            pB1.u[0] = pack2_trunc(p10, p11); pB1.u[1] = pack2_trunc(p12, p13);
            pB1.u[2] = pack2_trunc(p30, p31); pB1.u[3] = pack2_trunc(p32, p33);
            ls += __shfl_xor(ls, 16, 64);
            ls += __shfl_xor(ls, 32, 64);
            lB += ls;
        }

        // ---- PV for BOTH q-tiles; vb read ONCE ----
        #pragma unroll
        for (int dt = 0; dt < 4; dt++) {
            bf16x8 vb0 = *(const bf16x8*)&Vt[(dt * 16 + li) * LSTR + QD * 8];
            bf16x8 vb1 = *(const bf16x8*)&Vt[(dt * 16 + li) * LSTR + 32 + QD * 8];
            accA[dt] = __builtin_amdgcn_mfma_f32_16x16x32_bf16(pA0.v, vb0, accA[dt], 0, 0, 0);
            accA[dt] = __builtin_amdgcn_mfma_f32_16x16x32_bf16(pA1.v, vb1, accA[dt], 0, 0, 0);
            accB[dt] = __builtin_amdgcn_mfma_f32_16x16x32_bf16(pB0.v, vb0, accB[dt], 0, 0, 0);
            accB[dt] = __builtin_amdgcn_mfma_f32_16x16x32_bf16(pB1.v, vb1, accB[dt], 0, 0, 0);
        }
    }

    // ---- epilogue: both q-tiles ----
    {
        float invl = 1.0f / lA;
        float i0 = __shfl(invl, QD * 4 + 0, 64);
        float i1 = __shfl(invl, QD * 4 + 1, 64);
        float i2 = __shfl(invl, QD * 4 + 2, 64);
        float i3 = __shfl(invl, QD * 4 + 3, 64);
        float* ob = out + boff + (size_t)q0 * DIM;
        const int rbase = wave * 16 + QD * 4;
        #pragma unroll
        for (int dt = 0; dt < 4; dt++) {
            int col = dt * 16 + li;
            ob[(size_t)(rbase + 0) * DIM + col] = accA[dt][0] * i0;
            ob[(size_t)(rbase + 1) * DIM + col] = accA[dt][1] * i1;
            ob[(size_t)(rbase + 2) * DIM + col] = accA[dt][2] * i2;
            ob[(size_t)(rbase + 3) * DIM + col] = accA[dt][3] * i3;
        }
    }
    {
        float invl = 1.0f / lB;
        float i0 = __shfl(invl, QD * 4 + 0, 64);
        float i1 = __shfl(invl, QD * 4 + 1, 64);
        float i2 = __shfl(invl, QD * 4 + 2, 64);
        float i3 = __shfl(invl, QD * 4 + 3, 64);
        float* ob = out + boff + (size_t)(q0 + 64) * DIM;
        const int rbase = wave * 16 + QD * 4;
        #pragma unroll
        for (int dt = 0; dt < 4; dt++) {
            int col = dt * 16 + li;
            ob[(size_t)(rbase + 0) * DIM + col] = accB[dt][0] * i0;
            ob[(size_t)(rbase + 1) * DIM + col] = accB[dt][1] * i1;
            ob[(size_t)(rbase + 2) * DIM + col] = accB[dt][2] * i2;
            ob[(size_t)(rbase + 3) * DIM + col] = accB[dt][3] * i3;
        }
    }
}

extern "C" void kernel_launch(void* const* d_in, const int* in_sizes, int n_in,
                              void* d_out, int out_size, void* d_ws, size_t ws_size,
                              hipStream_t stream) {
    const float* q = (const float*)d_in[0];
    const float* k = (const float*)d_in[1];
    const float* v = (const float*)d_in[2];
    const int* valid_lens = (const int*)d_in[3];
    float* out = (float*)d_out;

    dim3 grid(BATCH * (SEQ / BQ));   // 64 x 8 = 512 blocks
    dim3 block(256);
    attn_mfma_flash5<<<grid, block, 0, stream>>>(q, k, v, valid_lens, out);
}